// Round 2
// baseline (1255.454 us; speedup 1.0000x reference)
//
#include <hip/hip_runtime.h>
#include <hip/hip_bf16.h>

#define L_SEQ 2048
#define DMODEL 1024
#define NHEAD 16
#define DHEAD 64
#define D3 3072

// ---------------- tiled fp32 GEMM: C = A @ B + bias, optional exact-GELU ----
// A: M x K (row-major fp32), B: K x N (fp32), bias: N (fp32)
// EPI: 0=none 1=GELU(exact).
template<int EPI>
__global__ __launch_bounds__(256) void gemm_bias(
    const float* __restrict__ A, const float* __restrict__ Bw,
    const float* __restrict__ bias, float* __restrict__ C,
    int M, int N, int K)
{
  const int BK = 16;
  __shared__ float As[BK][132];   // [k][m], pad 132: b128-aligned, 2-way banks
  __shared__ float Bs[BK][132];   // [k][n]
  int tx = threadIdx.x, ty = threadIdx.y;
  int tid = ty * 16 + tx;
  int row0 = blockIdx.y * 128, col0 = blockIdx.x * 128;
  float acc[8][8] = {};
  for (int k0 = 0; k0 < K; k0 += BK) {
    #pragma unroll
    for (int it = 0; it < 8; ++it) {
      int idx = tid + it * 256;
      int m = idx >> 4, kk = idx & 15;
      As[kk][m] = A[(size_t)(row0 + m) * K + k0 + kk];
    }
    #pragma unroll
    for (int it = 0; it < 8; ++it) {
      int idx = tid + it * 256;
      int kk = idx >> 7, n = idx & 127;
      Bs[kk][n] = Bw[(size_t)(k0 + kk) * N + col0 + n];
    }
    __syncthreads();
    #pragma unroll
    for (int kk = 0; kk < BK; ++kk) {
      float a[8], b[8];
      #pragma unroll
      for (int e = 0; e < 8; ++e) a[e] = As[kk][ty * 8 + e];
      #pragma unroll
      for (int e = 0; e < 8; ++e) b[e] = Bs[kk][tx * 8 + e];
      #pragma unroll
      for (int i = 0; i < 8; ++i)
        #pragma unroll
        for (int j = 0; j < 8; ++j) acc[i][j] += a[i] * b[j];
    }
    __syncthreads();
  }
  #pragma unroll
  for (int i = 0; i < 8; ++i) {
    int m = row0 + ty * 8 + i;
    #pragma unroll
    for (int j = 0; j < 8; ++j) {
      int n = col0 + tx * 8 + j;
      float v = acc[i][j] + bias[n];
      if (EPI == 1) v = 0.5f * v * (1.0f + erff(v * 0.70710678118654752f));
      C[(size_t)m * N + n] = v;
    }
  }
}

// ---------------- causal softmax attention, online-softmax, 1 wave/query ----
// qkv: (L, 3, H, d) fp32.  ysm out: (H, L, d) fp32.
__global__ __launch_bounds__(256) void attn_kernel(const float* __restrict__ qkv,
                                                   float* __restrict__ ysm)
{
  int h = blockIdx.y;
  int q0 = blockIdx.x * 4;          // 4 queries per block, 1 per wave
  int tid = threadIdx.x;
  int w = tid >> 6, lane = tid & 63;
  __shared__ float Ks[64][65];      // pad 65 -> 2-way bank aliasing (free)
  __shared__ float Vs[64][65];
  __shared__ float Qs[4][64];
  __shared__ float Ps[4][64];
  {
    int qi = tid >> 6, e = tid & 63;
    Qs[qi][e] = qkv[(size_t)(q0 + qi) * D3 + h * 64 + e];
  }
  int myq = q0 + w;
  float m = -1e30f, l = 0.f, o = 0.f;   // o: accumulator for dim = lane
  int ntiles = q0 / 64 + 1;             // covers keys 0..myq for all 4 waves
  for (int t0 = 0; t0 < ntiles; ++t0) {
    __syncthreads();
    for (int i = tid; i < 64 * 64; i += 256) {
      int t = i >> 6, e = i & 63;
      size_t base = (size_t)(t0 * 64 + t) * D3 + h * 64 + e;
      Ks[t][e] = qkv[base + 1024];
      Vs[t][e] = qkv[base + 2048];
    }
    __syncthreads();
    int tkey = t0 * 64 + lane;          // lane = key within tile
    float s = 0.f;
    #pragma unroll
    for (int e = 0; e < 64; ++e) s += Qs[w][e] * Ks[lane][e];
    s *= 0.125f;
    bool valid = (tkey <= myq);         // ref's -10000 underflows to 0 anyway
    s = valid ? s : -1e30f;
    float mt = s;
    #pragma unroll
    for (int off = 32; off; off >>= 1) mt = fmaxf(mt, __shfl_xor(mt, off));
    float mnew = fmaxf(m, mt);
    float p = valid ? __expf(s - mnew) : 0.f;
    float al = __expf(m - mnew);
    m = mnew;
    float ps = p;
    #pragma unroll
    for (int off = 32; off; off >>= 1) ps += __shfl_xor(ps, off);
    l = l * al + ps;
    Ps[w][lane] = p;
    __syncthreads();
    o *= al;
    #pragma unroll
    for (int t = 0; t < 64; ++t) o += Ps[w][t] * Vs[t][lane];
  }
  ysm[((size_t)h * L_SEQ + myq) * 64 + lane] = o / l;
}

// ---------------- STP branch ------------------------------------------------
// Elementwise-decay linear recurrence, chunked scan (chunk C=64, NC=32).
// states layout: [(h*32 + c)*4096 + i*64 + j]

// (a) per-(h,chunk) local decayed sums, zero init
__global__ __launch_bounds__(256) void stp_local(const float* __restrict__ qkv,
    const float* __restrict__ Lam, const float* __restrict__ Gam,
    float* __restrict__ states)
{
  int c = blockIdx.x, h = blockIdx.y;
  int tid = threadIdx.x;
  int i = tid >> 2, j0 = (tid & 3) * 16;
  __shared__ float Kc[64][64];   // [t][j], pre-scaled
  __shared__ float Vc[64][64];   // [t][i]
  for (int idx = tid; idx < 64 * 64; idx += 256) {
    int t = idx >> 6, e = idx & 63;
    size_t base = (size_t)(c * 64 + t) * D3 + h * 64 + e;
    Kc[t][e] = qkv[base + 1024] * 0.125f;
    Vc[t][e] = qkv[base + 2048];
  }
  float r[16], g[16], s[16];
  #pragma unroll
  for (int e = 0; e < 16; ++e) {
    int idx = h * 4096 + i * 64 + j0 + e;
    float lam = Lam[idx];
    r[e] = 1.f / (1.f + expf(lam));     // 1 - sigmoid(lam)
    g[e] = Gam[idx];
    s[e] = 0.f;
  }
  __syncthreads();
  for (int t = 0; t < 64; ++t) {
    float v = Vc[t][i];
    #pragma unroll
    for (int e = 0; e < 16; ++e)
      s[e] = r[e] * s[e] + g[e] * (v * Kc[t][j0 + e]);
  }
  #pragma unroll
  for (int e = 0; e < 16; ++e)
    states[((size_t)h * 32 + c) * 4096 + i * 64 + j0 + e] = s[e];
}

// (b) sequential combine across chunks; rewrites buffer to chunk-START states
__global__ __launch_bounds__(256) void stp_scan(const float* __restrict__ Lam,
                                                float* __restrict__ states)
{
  int gid = blockIdx.x * 256 + threadIdx.x;   // h*4096 + i*64 + j, 65536 total
  float lam = Lam[gid];
  float r = 1.f / (1.f + expf(lam));
  float r64 = r;
  #pragma unroll
  for (int q = 0; q < 6; ++q) r64 *= r64;     // r^64
  int h = gid >> 12, low = gid & 4095;
  float acc = 0.f;
  for (int c = 0; c < 32; ++c) {
    size_t idx = ((size_t)h * 32 + c) * 4096 + low;
    float dloc = states[idx];
    states[idx] = acc;                         // S_start(c)
    acc = r64 * acc + dloc;
  }
}

// (c) replay chunk from S_start, contract with q each step -> y_stp (H,L,d)
__global__ __launch_bounds__(256) void stp_out(const float* __restrict__ qkv,
    const float* __restrict__ Lam, const float* __restrict__ Gam,
    const float* __restrict__ Wst, const float* __restrict__ states,
    float* __restrict__ ystp)
{
  int c = blockIdx.x, h = blockIdx.y;
  int tid = threadIdx.x;
  int i = tid >> 2, j0 = (tid & 3) * 16;
  __shared__ float Kc[64][64];
  __shared__ float Vc[64][64];
  __shared__ float Qc[64][64];
  for (int idx = tid; idx < 64 * 64; idx += 256) {
    int t = idx >> 6, e = idx & 63;
    size_t base = (size_t)(c * 64 + t) * D3 + h * 64 + e;
    Qc[t][e] = qkv[base];
    Kc[t][e] = qkv[base + 1024] * 0.125f;
    Vc[t][e] = qkv[base + 2048];
  }
  float r[16], g[16], s[16], w[16];
  #pragma unroll
  for (int e = 0; e < 16; ++e) {
    int idx = h * 4096 + i * 64 + j0 + e;
    float lam = Lam[idx];
    r[e] = 1.f / (1.f + expf(lam));
    g[e] = Gam[idx];
    w[e] = Wst[idx];
    s[e] = states[((size_t)h * 32 + c) * 4096 + i * 64 + j0 + e];
  }
  __syncthreads();
  for (int t = 0; t < 64; ++t) {
    float v = Vc[t][i];
    float y = 0.f;
    #pragma unroll
    for (int e = 0; e < 16; ++e) {
      s[e] = r[e] * s[e] + g[e] * (v * Kc[t][j0 + e]);    // update first
      y += (w[e] + s[e]) * Qc[t][j0 + e];                 // then contract
    }
    y += __shfl_xor(y, 1);
    y += __shfl_xor(y, 2);
    if ((tid & 3) == 0)
      ystp[((size_t)h * L_SEQ + c * 64 + t) * 64 + i] = y;
  }
}

// ---------------- gate tail: g(L,512) @ w2(512,16) + b2 -> sigmoid ----------
__global__ __launch_bounds__(256) void gate2_kernel(const float* __restrict__ g,
    const float* __restrict__ w2, const float* __restrict__ b2,
    float* __restrict__ alpha)
{
  int gid = blockIdx.x * 256 + threadIdx.x;   // L*H = 32768
  int l = gid >> 4, h = gid & 15;
  float acc = b2[h];
  const float* grow = g + (size_t)l * 512;
  for (int c = 0; c < 512; ++c) acc += grow[c] * w2[c * 16 + h];
  alpha[gid] = 1.f / (1.f + expf(-acc));
}

// ---------------- combine + transpose to (L, D) -----------------------------
__global__ __launch_bounds__(256) void combine_kernel(const float* __restrict__ ysm,
    const float* __restrict__ ystp, const float* __restrict__ alpha,
    float* __restrict__ yc)
{
  int gid = blockIdx.x * 256 + threadIdx.x;   // 2M
  int l = gid >> 10, cidx = gid & 1023;
  int h = cidx >> 6, e = cidx & 63;
  float a = alpha[l * 16 + h];
  size_t src = ((size_t)h * L_SEQ + l) * 64 + e;
  yc[gid] = a * ysm[src] + (1.f - a) * ystp[src];
}

extern "C" void kernel_launch(void* const* d_in, const int* in_sizes, int n_in,
                              void* d_out, int out_size, void* d_ws, size_t ws_size,
                              hipStream_t stream) {
  (void)in_sizes; (void)n_in; (void)out_size; (void)ws_size;
  const float* x      = (const float*)d_in[0];
  const float* Wqkv_w = (const float*)d_in[1];
  const float* Wqkv_b = (const float*)d_in[2];
  const float* out_w  = (const float*)d_in[3];
  const float* out_b  = (const float*)d_in[4];
  const float* W_st   = (const float*)d_in[5];
  const float* Lam    = (const float*)d_in[6];
  const float* Gam    = (const float*)d_in[7];
  const float* gw1    = (const float*)d_in[8];
  const float* gb1    = (const float*)d_in[9];
  const float* gw2    = (const float*)d_in[10];
  const float* gb2    = (const float*)d_in[11];

  float* ws     = (float*)d_ws;
  float* qkv    = ws;                      // 2048*3072      = 6291456
  float* ysm    = qkv    + 6291456;        // 16*2048*64     = 2097152
  float* ystp   = ysm    + 2097152;        //                = 2097152
  float* states = ystp   + 2097152;        // 16*32*4096     = 2097152
  float* g      = states + 2097152;        // 2048*512       = 1048576
  float* alpha  = g      + 1048576;        // 2048*16        = 32768
  float* yc     = states;                  // reuse: states dead after stp_out

  // 1. qkv = x @ Wqkv_w + b    (2048 x 3072, K=1024)
  gemm_bias<0><<<dim3(24, 16), dim3(16, 16), 0, stream>>>(
      x, Wqkv_w, Wqkv_b, qkv, 2048, 3072, 1024);
  // 2. softmax branch
  attn_kernel<<<dim3(512, 16), 256, 0, stream>>>(qkv, ysm);
  // 3. STP branch
  stp_local<<<dim3(32, 16), 256, 0, stream>>>(qkv, Lam, Gam, states);
  stp_scan<<<dim3(256), 256, 0, stream>>>(Lam, states);
  stp_out<<<dim3(32, 16), 256, 0, stream>>>(qkv, Lam, Gam, W_st, states, ystp);
  // 4. gate
  gemm_bias<1><<<dim3(4, 16), dim3(16, 16), 0, stream>>>(
      x, gw1, gb1, g, 2048, 512, 1024);
  gate2_kernel<<<dim3(128), 256, 0, stream>>>(g, gw2, gb2, alpha);
  // 5. combine (writes yc over states)
  combine_kernel<<<dim3(8192), 256, 0, stream>>>(ysm, ystp, alpha, yc);
  // 6. out projection -> fp32 d_out
  gemm_bias<0><<<dim3(8, 16), dim3(16, 16), 0, stream>>>(
      yc, out_w, out_b, (float*)d_out, 2048, 1024, 1024);
}

// Round 3
// 751.724 us; speedup vs baseline: 1.6701x; 1.6701x over previous
//
#include <hip/hip_runtime.h>
#include <hip/hip_bf16.h>

#define L_SEQ 2048
#define DMODEL 1024
#define NHEAD 16
#define DHEAD 64
#define D3 3072

typedef __attribute__((ext_vector_type(8))) short s8v;   // 8 bf16 (4 VGPRs)
typedef __attribute__((ext_vector_type(4))) float f4v;   // MFMA acc

__device__ __forceinline__ short f2bf(float f) {
  __hip_bfloat16 h = __float2bfloat16(f);
  return *reinterpret_cast<short*>(&h);
}
__device__ __forceinline__ int pack2bf(float lo, float hi) {
  return (int)(((unsigned)(unsigned short)f2bf(hi) << 16) |
               (unsigned)(unsigned short)f2bf(lo));
}

// ---------------- tiled fp32 GEMM: C = A @ B + bias, optional exact-GELU ----
template<int EPI>
__global__ __launch_bounds__(256) void gemm_bias(
    const float* __restrict__ A, const float* __restrict__ Bw,
    const float* __restrict__ bias, float* __restrict__ C,
    int M, int N, int K)
{
  const int BK = 16;
  __shared__ float As[BK][132];
  __shared__ float Bs[BK][132];
  int tx = threadIdx.x, ty = threadIdx.y;
  int tid = ty * 16 + tx;
  int row0 = blockIdx.y * 128, col0 = blockIdx.x * 128;
  float acc[8][8] = {};
  for (int k0 = 0; k0 < K; k0 += BK) {
    #pragma unroll
    for (int it = 0; it < 8; ++it) {
      int idx = tid + it * 256;
      int m = idx >> 4, kk = idx & 15;
      As[kk][m] = A[(size_t)(row0 + m) * K + k0 + kk];
    }
    #pragma unroll
    for (int it = 0; it < 8; ++it) {
      int idx = tid + it * 256;
      int kk = idx >> 7, n = idx & 127;
      Bs[kk][n] = Bw[(size_t)(k0 + kk) * N + col0 + n];
    }
    __syncthreads();
    #pragma unroll
    for (int kk = 0; kk < BK; ++kk) {
      float a[8], b[8];
      #pragma unroll
      for (int e = 0; e < 8; ++e) a[e] = As[kk][ty * 8 + e];
      #pragma unroll
      for (int e = 0; e < 8; ++e) b[e] = Bs[kk][tx * 8 + e];
      #pragma unroll
      for (int i = 0; i < 8; ++i)
        #pragma unroll
        for (int j = 0; j < 8; ++j) acc[i][j] += a[i] * b[j];
    }
    __syncthreads();
  }
  #pragma unroll
  for (int i = 0; i < 8; ++i) {
    int m = row0 + ty * 8 + i;
    #pragma unroll
    for (int j = 0; j < 8; ++j) {
      int n = col0 + tx * 8 + j;
      float v = acc[i][j] + bias[n];
      if (EPI == 1) v = 0.5f * v * (1.0f + erff(v * 0.70710678118654752f));
      C[(size_t)m * N + n] = v;
    }
  }
}

// ---------------- bf16 MFMA flash attention ---------------------------------
// Computes S^T = K·Q^T so A/B frags are both row-major loads; online softmax
// state is per-column (lane-uniform alpha); O^T = V^T·P^T with wave-private
// P round-trip through LDS. qkv: (L,3,H,d) fp32. ysm: (H,L,d) fp32.
__global__ __launch_bounds__(256) void attn_mfma(const float* __restrict__ qkv,
                                                 float* __restrict__ ysm)
{
  const int bid = blockIdx.x;
  const int h  = bid & 15;          // h fast: pairs (c, c+256) differ in qt by 16
  const int qt = bid >> 4;
  const int q0 = qt * 64;
  const int nt = qt + 1;            // causal: key tiles 0..qt
  const int tid = threadIdx.x;
  const int w = tid >> 6, lane = tid & 63;
  const int quad = lane >> 4, c = lane & 15;

  __shared__ __align__(16) char smem[27648];
  short* Ks = (short*)smem;          // [key][dim]  stride 72  (9216 B)
  short* Vt = Ks + 4608;             // [dim][key]  stride 72  (9216 B)
  short* Ps = Vt + 4608;             // [wave][q=16][key=64] stride 72 (9216 B)
  float* Ob = (float*)smem;          // [q=64][dim] stride 66 — overlays Ks/Vt

  const int qrow = q0 + w * 16 + c;
  // Q fragments (B-operand): lane holds Q[c][kc*32 + quad*8 + j]
  s8v qf[2];
  {
    const float* qp = qkv + (size_t)qrow * D3 + h * 64 + quad * 8;
    #pragma unroll
    for (int kc = 0; kc < 2; ++kc) {
      #pragma unroll
      for (int j = 0; j < 8; ++j) qf[kc][j] = f2bf(qp[kc * 32 + j]);
    }
  }

  f4v o_acc[4] = {};                 // O^T[dim subtile mt][reg]  (col = query c)
  float m = -1e30f, l = 0.f;

  for (int t0 = 0; t0 < nt; ++t0) {
    __syncthreads();
    // stage K (row-major bf16) and V^T (transposed bf16)
    for (int i = tid; i < 2048; i += 256) {
      int t = i >> 5, e2 = i & 31;
      size_t base = (size_t)(t0 * 64 + t) * D3 + h * 64 + e2 * 2;
      float2 kv = *(const float2*)(qkv + base + 1024);
      float2 vv = *(const float2*)(qkv + base + 2048);
      *(int*)&Ks[t * 72 + e2 * 2] = pack2bf(kv.x, kv.y);
      Vt[(e2 * 2) * 72 + t]     = f2bf(vv.x);
      Vt[(e2 * 2 + 1) * 72 + t] = f2bf(vv.y);
    }
    __syncthreads();

    // S^T = K·Q^T : 4 key-subtiles × 2 k-chunks
    f4v s_acc[4] = {};
    #pragma unroll
    for (int kt = 0; kt < 4; ++kt) {
      #pragma unroll
      for (int kc = 0; kc < 2; ++kc) {
        s8v kf = *(s8v*)&Ks[(kt * 16 + c) * 72 + kc * 32 + quad * 8];
        s_acc[kt] = __builtin_amdgcn_mfma_f32_16x16x32_bf16(kf, qf[kc], s_acc[kt], 0, 0, 0);
      }
    }
    // scale + causal mask  (key = t0*64 + kt*16 + quad*4 + r ; query = qrow)
    float sv[4][4];
    bool full = (t0 * 64 + 63) <= (q0 + w * 16);   // wave-uniform full-tile test
    #pragma unroll
    for (int kt = 0; kt < 4; ++kt)
      #pragma unroll
      for (int r = 0; r < 4; ++r) {
        float s = s_acc[kt][r] * 0.125f;
        if (!full) {
          int key = t0 * 64 + kt * 16 + quad * 4 + r;
          s = (key <= qrow) ? s : -1e30f;
        }
        sv[kt][r] = s;
      }
    // online softmax (per query column; reduce over quads via xor 16,32)
    float mloc = -1e30f;
    #pragma unroll
    for (int kt = 0; kt < 4; ++kt)
      #pragma unroll
      for (int r = 0; r < 4; ++r) mloc = fmaxf(mloc, sv[kt][r]);
    mloc = fmaxf(mloc, __shfl_xor(mloc, 16));
    mloc = fmaxf(mloc, __shfl_xor(mloc, 32));
    float mnew = fmaxf(m, mloc);
    float alpha = __expf(m - mnew);
    m = mnew;
    float p[4][4], ls = 0.f;
    #pragma unroll
    for (int kt = 0; kt < 4; ++kt)
      #pragma unroll
      for (int r = 0; r < 4; ++r) { p[kt][r] = __expf(sv[kt][r] - mnew); ls += p[kt][r]; }
    ls += __shfl_xor(ls, 16);
    ls += __shfl_xor(ls, 32);
    l = l * alpha + ls;
    #pragma unroll
    for (int mt = 0; mt < 4; ++mt)
      #pragma unroll
      for (int r = 0; r < 4; ++r) o_acc[mt][r] *= alpha;
    // P^T -> LDS (wave-private, row = query c, col = key), packed b64 stores
    short* Pw = Ps + w * 1152;
    #pragma unroll
    for (int kt = 0; kt < 4; ++kt) {
      short pk[4];
      #pragma unroll
      for (int r = 0; r < 4; ++r) pk[r] = f2bf(p[kt][r]);
      *(int*)&Pw[c * 72 + kt * 16 + quad * 4]     = ((int)(unsigned short)pk[0]) | ((int)(unsigned short)pk[1] << 16);
      *(int*)&Pw[c * 72 + kt * 16 + quad * 4 + 2] = ((int)(unsigned short)pk[2]) | ((int)(unsigned short)pk[3] << 16);
    }
    // O^T += V^T · P^T
    #pragma unroll
    for (int kc2 = 0; kc2 < 2; ++kc2) {
      s8v pf = *(s8v*)&Pw[c * 72 + kc2 * 32 + quad * 8];
      #pragma unroll
      for (int mt = 0; mt < 4; ++mt) {
        s8v vf = *(s8v*)&Vt[(mt * 16 + c) * 72 + kc2 * 32 + quad * 8];
        o_acc[mt] = __builtin_amdgcn_mfma_f32_16x16x32_bf16(vf, pf, o_acc[mt], 0, 0, 0);
      }
    }
  }

  float rinv = 1.f / l;
  __syncthreads();                   // all K/V reads done; overlay Ob
  #pragma unroll
  for (int mt = 0; mt < 4; ++mt)
    #pragma unroll
    for (int r = 0; r < 4; ++r)
      Ob[(w * 16 + c) * 66 + mt * 16 + quad * 4 + r] = o_acc[mt][r] * rinv;
  __syncthreads();
  for (int i = tid; i < 4096; i += 256) {
    int q = i >> 6, e = i & 63;
    ysm[((size_t)h * L_SEQ + q0 + q) * 64 + e] = Ob[q * 66 + e];
  }
}

// ---------------- STP branch (unchanged) ------------------------------------
__global__ __launch_bounds__(256) void stp_local(const float* __restrict__ qkv,
    const float* __restrict__ Lam, const float* __restrict__ Gam,
    float* __restrict__ states)
{
  int c = blockIdx.x, h = blockIdx.y;
  int tid = threadIdx.x;
  int i = tid >> 2, j0 = (tid & 3) * 16;
  __shared__ float Kc[64][64];
  __shared__ float Vc[64][64];
  for (int idx = tid; idx < 64 * 64; idx += 256) {
    int t = idx >> 6, e = idx & 63;
    size_t base = (size_t)(c * 64 + t) * D3 + h * 64 + e;
    Kc[t][e] = qkv[base + 1024] * 0.125f;
    Vc[t][e] = qkv[base + 2048];
  }
  float r[16], g[16], s[16];
  #pragma unroll
  for (int e = 0; e < 16; ++e) {
    int idx = h * 4096 + i * 64 + j0 + e;
    float lam = Lam[idx];
    r[e] = 1.f / (1.f + expf(lam));
    g[e] = Gam[idx];
    s[e] = 0.f;
  }
  __syncthreads();
  for (int t = 0; t < 64; ++t) {
    float v = Vc[t][i];
    #pragma unroll
    for (int e = 0; e < 16; ++e)
      s[e] = r[e] * s[e] + g[e] * (v * Kc[t][j0 + e]);
  }
  #pragma unroll
  for (int e = 0; e < 16; ++e)
    states[((size_t)h * 32 + c) * 4096 + i * 64 + j0 + e] = s[e];
}

__global__ __launch_bounds__(256) void stp_scan(const float* __restrict__ Lam,
                                                float* __restrict__ states)
{
  int gid = blockIdx.x * 256 + threadIdx.x;
  float lam = Lam[gid];
  float r = 1.f / (1.f + expf(lam));
  float r64 = r;
  #pragma unroll
  for (int q = 0; q < 6; ++q) r64 *= r64;
  int h = gid >> 12, low = gid & 4095;
  float acc = 0.f;
  for (int c = 0; c < 32; ++c) {
    size_t idx = ((size_t)h * 32 + c) * 4096 + low;
    float dloc = states[idx];
    states[idx] = acc;
    acc = r64 * acc + dloc;
  }
}

__global__ __launch_bounds__(256) void stp_out(const float* __restrict__ qkv,
    const float* __restrict__ Lam, const float* __restrict__ Gam,
    const float* __restrict__ Wst, const float* __restrict__ states,
    float* __restrict__ ystp)
{
  int c = blockIdx.x, h = blockIdx.y;
  int tid = threadIdx.x;
  int i = tid >> 2, j0 = (tid & 3) * 16;
  __shared__ float Kc[64][64];
  __shared__ float Vc[64][64];
  __shared__ float Qc[64][64];
  for (int idx = tid; idx < 64 * 64; idx += 256) {
    int t = idx >> 6, e = idx & 63;
    size_t base = (size_t)(c * 64 + t) * D3 + h * 64 + e;
    Qc[t][e] = qkv[base];
    Kc[t][e] = qkv[base + 1024] * 0.125f;
    Vc[t][e] = qkv[base + 2048];
  }
  float r[16], g[16], s[16], w[16];
  #pragma unroll
  for (int e = 0; e < 16; ++e) {
    int idx = h * 4096 + i * 64 + j0 + e;
    float lam = Lam[idx];
    r[e] = 1.f / (1.f + expf(lam));
    g[e] = Gam[idx];
    w[e] = Wst[idx];
    s[e] = states[((size_t)h * 32 + c) * 4096 + i * 64 + j0 + e];
  }
  __syncthreads();
  for (int t = 0; t < 64; ++t) {
    float v = Vc[t][i];
    float y = 0.f;
    #pragma unroll
    for (int e = 0; e < 16; ++e) {
      s[e] = r[e] * s[e] + g[e] * (v * Kc[t][j0 + e]);
      y += (w[e] + s[e]) * Qc[t][j0 + e];
    }
    y += __shfl_xor(y, 1);
    y += __shfl_xor(y, 2);
    if ((tid & 3) == 0)
      ystp[((size_t)h * L_SEQ + c * 64 + t) * 64 + i] = y;
  }
}

// ---------------- gate tail --------------------------------------------------
__global__ __launch_bounds__(256) void gate2_kernel(const float* __restrict__ g,
    const float* __restrict__ w2, const float* __restrict__ b2,
    float* __restrict__ alpha)
{
  int gid = blockIdx.x * 256 + threadIdx.x;
  int l = gid >> 4, h = gid & 15;
  float acc = b2[h];
  const float* grow = g + (size_t)l * 512;
  for (int c = 0; c < 512; ++c) acc += grow[c] * w2[c * 16 + h];
  alpha[gid] = 1.f / (1.f + expf(-acc));
}

// ---------------- combine + transpose ---------------------------------------
__global__ __launch_bounds__(256) void combine_kernel(const float* __restrict__ ysm,
    const float* __restrict__ ystp, const float* __restrict__ alpha,
    float* __restrict__ yc)
{
  int gid = blockIdx.x * 256 + threadIdx.x;
  int l = gid >> 10, cidx = gid & 1023;
  int h = cidx >> 6, e = cidx & 63;
  float a = alpha[l * 16 + h];
  size_t src = ((size_t)h * L_SEQ + l) * 64 + e;
  yc[gid] = a * ysm[src] + (1.f - a) * ystp[src];
}

extern "C" void kernel_launch(void* const* d_in, const int* in_sizes, int n_in,
                              void* d_out, int out_size, void* d_ws, size_t ws_size,
                              hipStream_t stream) {
  (void)in_sizes; (void)n_in; (void)out_size; (void)ws_size;
  const float* x      = (const float*)d_in[0];
  const float* Wqkv_w = (const float*)d_in[1];
  const float* Wqkv_b = (const float*)d_in[2];
  const float* out_w  = (const float*)d_in[3];
  const float* out_b  = (const float*)d_in[4];
  const float* W_st   = (const float*)d_in[5];
  const float* Lam    = (const float*)d_in[6];
  const float* Gam    = (const float*)d_in[7];
  const float* gw1    = (const float*)d_in[8];
  const float* gb1    = (const float*)d_in[9];
  const float* gw2    = (const float*)d_in[10];
  const float* gb2    = (const float*)d_in[11];

  float* ws     = (float*)d_ws;
  float* qkv    = ws;
  float* ysm    = qkv    + 6291456;
  float* ystp   = ysm    + 2097152;
  float* states = ystp   + 2097152;
  float* g      = states + 2097152;
  float* alpha  = g      + 1048576;
  float* yc     = states;

  gemm_bias<0><<<dim3(24, 16), dim3(16, 16), 0, stream>>>(
      x, Wqkv_w, Wqkv_b, qkv, 2048, 3072, 1024);
  attn_mfma<<<dim3(512), 256, 0, stream>>>(qkv, ysm);
  stp_local<<<dim3(32, 16), 256, 0, stream>>>(qkv, Lam, Gam, states);
  stp_scan<<<dim3(256), 256, 0, stream>>>(Lam, states);
  stp_out<<<dim3(32, 16), 256, 0, stream>>>(qkv, Lam, Gam, W_st, states, ystp);
  gemm_bias<1><<<dim3(4, 16), dim3(16, 16), 0, stream>>>(
      x, gw1, gb1, g, 2048, 512, 1024);
  gate2_kernel<<<dim3(128), 256, 0, stream>>>(g, gw2, gb2, alpha);
  combine_kernel<<<dim3(8192), 256, 0, stream>>>(ysm, ystp, alpha, yc);
  gemm_bias<0><<<dim3(8, 16), dim3(16, 16), 0, stream>>>(
      yc, out_w, out_b, (float*)d_out, 2048, 1024, 1024);
}

// Round 4
// 379.699 us; speedup vs baseline: 3.3064x; 1.9798x over previous
//
#include <hip/hip_runtime.h>
#include <hip/hip_bf16.h>

#define L_SEQ 2048
#define DMODEL 1024
#define NHEAD 16
#define DHEAD 64
#define D3 3072

typedef __attribute__((ext_vector_type(8))) short s8v;   // 8 bf16 (4 VGPRs)
typedef __attribute__((ext_vector_type(4))) float f4v;   // MFMA acc
typedef unsigned int u32;

__device__ __forceinline__ short f2bf(float f) {
  __hip_bfloat16 h = __float2bfloat16(f);
  return *reinterpret_cast<short*>(&h);
}
__device__ __forceinline__ int pack2bf(float lo, float hi) {
  return (int)(((unsigned)(unsigned short)f2bf(hi) << 16) |
               (unsigned)(unsigned short)f2bf(lo));
}

// ---------------- x -> bf16 (row-major) -------------------------------------
__global__ __launch_bounds__(256) void conv_x(const float* __restrict__ x,
                                              short* __restrict__ xb)
{
  int i = (blockIdx.x * 256 + threadIdx.x) * 4;
  float4 v = *(const float4*)(x + i);
  short4 o;
  o.x = f2bf(v.x); o.y = f2bf(v.y); o.z = f2bf(v.z); o.w = f2bf(v.w);
  *(short4*)(xb + i) = o;
}

// ---------------- W (K x N fp32) -> W^T (N x K bf16) ------------------------
__global__ __launch_bounds__(256) void transpose_conv(const float* __restrict__ W,
    short* __restrict__ Wt, int K, int N)
{
  __shared__ float T[32][33];
  int bx = blockIdx.x, by = blockIdx.y;      // bx: N/32, by: K/32
  int col = threadIdx.x & 31, rb = threadIdx.x >> 5;
  #pragma unroll
  for (int it = 0; it < 4; ++it) {
    int r = it * 8 + rb;
    T[r][col] = W[(size_t)(by * 32 + r) * N + bx * 32 + col];
  }
  __syncthreads();
  #pragma unroll
  for (int it = 0; it < 4; ++it) {
    int r = it * 8 + rb;
    Wt[(size_t)(bx * 32 + r) * K + by * 32 + col] = f2bf(T[col][r]);
  }
}

// ---------------- bf16 MFMA GEMM (m97 structure) ----------------------------
// C = A @ B + bias.  A: M x K bf16 row-major.  Bt: N x K bf16 (B transposed).
// 128x128 tile, BK=32, global_load_lds width=16, 4 waves x 64x64 quadrant.
// EPI: 0=none 1=exact GELU. Output fp32.
template<int EPI>
__global__ __launch_bounds__(256) void gemm_mfma(
    const short* __restrict__ A, const short* __restrict__ Bt,
    const float* __restrict__ bias, float* __restrict__ C,
    int M, int N, int K)
{
  __shared__ __align__(16) short As[128 * 32];   // [m][k] unpadded (8 KB)
  __shared__ __align__(16) short Bs[128 * 32];   // [n][k] unpadded (8 KB)
  const int tid = threadIdx.x;
  const int w = tid >> 6, lane = tid & 63;
  const int quad = lane >> 4, c = lane & 15;
  const int m0 = blockIdx.y * 128, n0 = blockIdx.x * 128;
  const int wm = (w & 1) * 64, wn = (w >> 1) * 64;
  f4v acc[4][4] = {};

  // staging geometry: byte offset in 8KB tile = (w*2+it)*1024 + lane*16
  int off0 = (w * 2) * 1024 + lane * 16;
  int row0s = off0 >> 6, colh0 = (off0 & 63) >> 1;   // row, halfword-in-row
  int off1 = off0 + 1024;
  int row1s = off1 >> 6, colh1 = (off1 & 63) >> 1;

  for (int k0 = 0; k0 < K; k0 += 32) {
    const short* gA0 = A + (size_t)(m0 + row0s) * K + k0 + colh0;
    const short* gA1 = A + (size_t)(m0 + row1s) * K + k0 + colh1;
    const short* gB0 = Bt + (size_t)(n0 + row0s) * K + k0 + colh0;
    const short* gB1 = Bt + (size_t)(n0 + row1s) * K + k0 + colh1;
    __builtin_amdgcn_global_load_lds(
        (const __attribute__((address_space(1))) u32*)gA0,
        (__attribute__((address_space(3))) u32*)(As + (w * 2) * 512), 16, 0, 0);
    __builtin_amdgcn_global_load_lds(
        (const __attribute__((address_space(1))) u32*)gA1,
        (__attribute__((address_space(3))) u32*)(As + (w * 2 + 1) * 512), 16, 0, 0);
    __builtin_amdgcn_global_load_lds(
        (const __attribute__((address_space(1))) u32*)gB0,
        (__attribute__((address_space(3))) u32*)(Bs + (w * 2) * 512), 16, 0, 0);
    __builtin_amdgcn_global_load_lds(
        (const __attribute__((address_space(1))) u32*)gB1,
        (__attribute__((address_space(3))) u32*)(Bs + (w * 2 + 1) * 512), 16, 0, 0);
    __syncthreads();                       // drains vmcnt before barrier
    s8v af[4], bf[4];
    #pragma unroll
    for (int mt = 0; mt < 4; ++mt)
      af[mt] = *(s8v*)&As[(wm + mt * 16 + c) * 32 + quad * 8];
    #pragma unroll
    for (int nt = 0; nt < 4; ++nt)
      bf[nt] = *(s8v*)&Bs[(wn + nt * 16 + c) * 32 + quad * 8];
    #pragma unroll
    for (int mt = 0; mt < 4; ++mt)
      #pragma unroll
      for (int nt = 0; nt < 4; ++nt)
        acc[mt][nt] = __builtin_amdgcn_mfma_f32_16x16x32_bf16(
            af[mt], bf[nt], acc[mt][nt], 0, 0, 0);
    __syncthreads();
  }
  #pragma unroll
  for (int mt = 0; mt < 4; ++mt)
    #pragma unroll
    for (int r = 0; r < 4; ++r) {
      int m = m0 + wm + mt * 16 + quad * 4 + r;
      #pragma unroll
      for (int nt = 0; nt < 4; ++nt) {
        int n = n0 + wn + nt * 16 + c;
        float v = acc[mt][nt][r] + bias[n];
        if (EPI == 1) v = 0.5f * v * (1.0f + erff(v * 0.70710678118654752f));
        C[(size_t)m * N + n] = v;
      }
    }
}

// ---------------- bf16 MFMA flash attention (unchanged) ---------------------
__global__ __launch_bounds__(256) void attn_mfma(const float* __restrict__ qkv,
                                                 float* __restrict__ ysm)
{
  const int bid = blockIdx.x;
  const int h  = bid & 15;
  const int qt = bid >> 4;
  const int q0 = qt * 64;
  const int nt = qt + 1;
  const int tid = threadIdx.x;
  const int w = tid >> 6, lane = tid & 63;
  const int quad = lane >> 4, c = lane & 15;

  __shared__ __align__(16) char smem[27648];
  short* Ks = (short*)smem;
  short* Vt = Ks + 4608;
  short* Ps = Vt + 4608;
  float* Ob = (float*)smem;

  const int qrow = q0 + w * 16 + c;
  s8v qf[2];
  {
    const float* qp = qkv + (size_t)qrow * D3 + h * 64 + quad * 8;
    #pragma unroll
    for (int kc = 0; kc < 2; ++kc) {
      #pragma unroll
      for (int j = 0; j < 8; ++j) qf[kc][j] = f2bf(qp[kc * 32 + j]);
    }
  }

  f4v o_acc[4] = {};
  float m = -1e30f, l = 0.f;

  for (int t0 = 0; t0 < nt; ++t0) {
    __syncthreads();
    for (int i = tid; i < 2048; i += 256) {
      int t = i >> 5, e2 = i & 31;
      size_t base = (size_t)(t0 * 64 + t) * D3 + h * 64 + e2 * 2;
      float2 kv = *(const float2*)(qkv + base + 1024);
      float2 vv = *(const float2*)(qkv + base + 2048);
      *(int*)&Ks[t * 72 + e2 * 2] = pack2bf(kv.x, kv.y);
      Vt[(e2 * 2) * 72 + t]     = f2bf(vv.x);
      Vt[(e2 * 2 + 1) * 72 + t] = f2bf(vv.y);
    }
    __syncthreads();

    f4v s_acc[4] = {};
    #pragma unroll
    for (int kt = 0; kt < 4; ++kt) {
      #pragma unroll
      for (int kc = 0; kc < 2; ++kc) {
        s8v kf = *(s8v*)&Ks[(kt * 16 + c) * 72 + kc * 32 + quad * 8];
        s_acc[kt] = __builtin_amdgcn_mfma_f32_16x16x32_bf16(kf, qf[kc], s_acc[kt], 0, 0, 0);
      }
    }
    float sv[4][4];
    bool full = (t0 * 64 + 63) <= (q0 + w * 16);
    #pragma unroll
    for (int kt = 0; kt < 4; ++kt)
      #pragma unroll
      for (int r = 0; r < 4; ++r) {
        float s = s_acc[kt][r] * 0.125f;
        if (!full) {
          int key = t0 * 64 + kt * 16 + quad * 4 + r;
          s = (key <= qrow) ? s : -1e30f;
        }
        sv[kt][r] = s;
      }
    float mloc = -1e30f;
    #pragma unroll
    for (int kt = 0; kt < 4; ++kt)
      #pragma unroll
      for (int r = 0; r < 4; ++r) mloc = fmaxf(mloc, sv[kt][r]);
    mloc = fmaxf(mloc, __shfl_xor(mloc, 16));
    mloc = fmaxf(mloc, __shfl_xor(mloc, 32));
    float mnew = fmaxf(m, mloc);
    float alpha = __expf(m - mnew);
    m = mnew;
    float p[4][4], ls = 0.f;
    #pragma unroll
    for (int kt = 0; kt < 4; ++kt)
      #pragma unroll
      for (int r = 0; r < 4; ++r) { p[kt][r] = __expf(sv[kt][r] - mnew); ls += p[kt][r]; }
    ls += __shfl_xor(ls, 16);
    ls += __shfl_xor(ls, 32);
    l = l * alpha + ls;
    #pragma unroll
    for (int mt = 0; mt < 4; ++mt)
      #pragma unroll
      for (int r = 0; r < 4; ++r) o_acc[mt][r] *= alpha;
    short* Pw = Ps + w * 1152;
    #pragma unroll
    for (int kt = 0; kt < 4; ++kt) {
      short pk[4];
      #pragma unroll
      for (int r = 0; r < 4; ++r) pk[r] = f2bf(p[kt][r]);
      *(int*)&Pw[c * 72 + kt * 16 + quad * 4]     = ((int)(unsigned short)pk[0]) | ((int)(unsigned short)pk[1] << 16);
      *(int*)&Pw[c * 72 + kt * 16 + quad * 4 + 2] = ((int)(unsigned short)pk[2]) | ((int)(unsigned short)pk[3] << 16);
    }
    #pragma unroll
    for (int kc2 = 0; kc2 < 2; ++kc2) {
      s8v pf = *(s8v*)&Pw[c * 72 + kc2 * 32 + quad * 8];
      #pragma unroll
      for (int mt = 0; mt < 4; ++mt) {
        s8v vf = *(s8v*)&Vt[(mt * 16 + c) * 72 + kc2 * 32 + quad * 8];
        o_acc[mt] = __builtin_amdgcn_mfma_f32_16x16x32_bf16(vf, pf, o_acc[mt], 0, 0, 0);
      }
    }
  }

  float rinv = 1.f / l;
  __syncthreads();
  #pragma unroll
  for (int mt = 0; mt < 4; ++mt)
    #pragma unroll
    for (int r = 0; r < 4; ++r)
      Ob[(w * 16 + c) * 66 + mt * 16 + quad * 4 + r] = o_acc[mt][r] * rinv;
  __syncthreads();
  for (int i = tid; i < 4096; i += 256) {
    int q = i >> 6, e = i & 63;
    ysm[((size_t)h * L_SEQ + q0 + q) * 64 + e] = Ob[q * 66 + e];
  }
}

// ---------------- STP branch (unchanged) ------------------------------------
__global__ __launch_bounds__(256) void stp_local(const float* __restrict__ qkv,
    const float* __restrict__ Lam, const float* __restrict__ Gam,
    float* __restrict__ states)
{
  int c = blockIdx.x, h = blockIdx.y;
  int tid = threadIdx.x;
  int i = tid >> 2, j0 = (tid & 3) * 16;
  __shared__ float Kc[64][64];
  __shared__ float Vc[64][64];
  for (int idx = tid; idx < 64 * 64; idx += 256) {
    int t = idx >> 6, e = idx & 63;
    size_t base = (size_t)(c * 64 + t) * D3 + h * 64 + e;
    Kc[t][e] = qkv[base + 1024] * 0.125f;
    Vc[t][e] = qkv[base + 2048];
  }
  float r[16], g[16], s[16];
  #pragma unroll
  for (int e = 0; e < 16; ++e) {
    int idx = h * 4096 + i * 64 + j0 + e;
    float lam = Lam[idx];
    r[e] = 1.f / (1.f + expf(lam));
    g[e] = Gam[idx];
    s[e] = 0.f;
  }
  __syncthreads();
  for (int t = 0; t < 64; ++t) {
    float v = Vc[t][i];
    #pragma unroll
    for (int e = 0; e < 16; ++e)
      s[e] = r[e] * s[e] + g[e] * (v * Kc[t][j0 + e]);
  }
  #pragma unroll
  for (int e = 0; e < 16; ++e)
    states[((size_t)h * 32 + c) * 4096 + i * 64 + j0 + e] = s[e];
}

__global__ __launch_bounds__(256) void stp_scan(const float* __restrict__ Lam,
                                                float* __restrict__ states)
{
  int gid = blockIdx.x * 256 + threadIdx.x;
  float lam = Lam[gid];
  float r = 1.f / (1.f + expf(lam));
  float r64 = r;
  #pragma unroll
  for (int q = 0; q < 6; ++q) r64 *= r64;
  int h = gid >> 12, low = gid & 4095;
  float acc = 0.f;
  for (int c = 0; c < 32; ++c) {
    size_t idx = ((size_t)h * 32 + c) * 4096 + low;
    float dloc = states[idx];
    states[idx] = acc;
    acc = r64 * acc + dloc;
  }
}

__global__ __launch_bounds__(256) void stp_out(const float* __restrict__ qkv,
    const float* __restrict__ Lam, const float* __restrict__ Gam,
    const float* __restrict__ Wst, const float* __restrict__ states,
    float* __restrict__ ystp)
{
  int c = blockIdx.x, h = blockIdx.y;
  int tid = threadIdx.x;
  int i = tid >> 2, j0 = (tid & 3) * 16;
  __shared__ float Kc[64][64];
  __shared__ float Vc[64][64];
  __shared__ float Qc[64][64];
  for (int idx = tid; idx < 64 * 64; idx += 256) {
    int t = idx >> 6, e = idx & 63;
    size_t base = (size_t)(c * 64 + t) * D3 + h * 64 + e;
    Qc[t][e] = qkv[base];
    Kc[t][e] = qkv[base + 1024] * 0.125f;
    Vc[t][e] = qkv[base + 2048];
  }
  float r[16], g[16], s[16], w[16];
  #pragma unroll
  for (int e = 0; e < 16; ++e) {
    int idx = h * 4096 + i * 64 + j0 + e;
    float lam = Lam[idx];
    r[e] = 1.f / (1.f + expf(lam));
    g[e] = Gam[idx];
    w[e] = Wst[idx];
    s[e] = states[((size_t)h * 32 + c) * 4096 + i * 64 + j0 + e];
  }
  __syncthreads();
  for (int t = 0; t < 64; ++t) {
    float v = Vc[t][i];
    float y = 0.f;
    #pragma unroll
    for (int e = 0; e < 16; ++e) {
      s[e] = r[e] * s[e] + g[e] * (v * Kc[t][j0 + e]);
      y += (w[e] + s[e]) * Qc[t][j0 + e];
    }
    y += __shfl_xor(y, 1);
    y += __shfl_xor(y, 2);
    if ((tid & 3) == 0)
      ystp[((size_t)h * L_SEQ + c * 64 + t) * 64 + i] = y;
  }
}

// ---------------- gate tail --------------------------------------------------
__global__ __launch_bounds__(256) void gate2_kernel(const float* __restrict__ g,
    const float* __restrict__ w2, const float* __restrict__ b2,
    float* __restrict__ alpha)
{
  int gid = blockIdx.x * 256 + threadIdx.x;
  int l = gid >> 4, h = gid & 15;
  float acc = b2[h];
  const float* grow = g + (size_t)l * 512;
  for (int c = 0; c < 512; ++c) acc += grow[c] * w2[c * 16 + h];
  alpha[gid] = 1.f / (1.f + expf(-acc));
}

// ---------------- combine + transpose -> bf16 (L, D) ------------------------
__global__ __launch_bounds__(256) void combine_kernel(const float* __restrict__ ysm,
    const float* __restrict__ ystp, const float* __restrict__ alpha,
    short* __restrict__ ycb)
{
  int gid = blockIdx.x * 256 + threadIdx.x;
  int l = gid >> 10, cidx = gid & 1023;
  int h = cidx >> 6, e = cidx & 63;
  float a = alpha[l * 16 + h];
  size_t src = ((size_t)h * L_SEQ + l) * 64 + e;
  ycb[gid] = f2bf(a * ysm[src] + (1.f - a) * ystp[src]);
}

extern "C" void kernel_launch(void* const* d_in, const int* in_sizes, int n_in,
                              void* d_out, int out_size, void* d_ws, size_t ws_size,
                              hipStream_t stream) {
  (void)in_sizes; (void)n_in; (void)out_size; (void)ws_size;
  const float* x      = (const float*)d_in[0];
  const float* Wqkv_w = (const float*)d_in[1];
  const float* Wqkv_b = (const float*)d_in[2];
  const float* out_w  = (const float*)d_in[3];
  const float* out_b  = (const float*)d_in[4];
  const float* W_st   = (const float*)d_in[5];
  const float* Lam    = (const float*)d_in[6];
  const float* Gam    = (const float*)d_in[7];
  const float* gw1    = (const float*)d_in[8];
  const float* gb1    = (const float*)d_in[9];
  const float* gw2    = (const float*)d_in[10];
  const float* gb2    = (const float*)d_in[11];

  float* ws     = (float*)d_ws;
  float* qkv    = ws;                      // 6291456 f
  float* ysm    = qkv    + 6291456;        // 2097152 f
  float* ystp   = ysm    + 2097152;        // 2097152 f
  float* states = ystp   + 2097152;        // 2097152 f
  float* g      = states + 2097152;        // 1048576 f
  float* alpha  = g      + 1048576;        //   32768 f
  short* xb     = (short*)(alpha + 32768); // 2097152 bf16 = 1048576 f
  short* wt_buf = xb + 2097152;            // up to 3145728 bf16 = 1572864 f
  short* ycb    = (short*)states;          // overlays states (dead after stp_out)
  // total ws: 16,285,696 floats = 65.1 MB

  // bf16 conversions / transposes (stream-ordered reuse of wt_buf)
  conv_x<<<dim3(2048), 256, 0, stream>>>(x, xb);
  transpose_conv<<<dim3(96, 32), 256, 0, stream>>>(Wqkv_w, wt_buf, 1024, 3072);
  // 1. qkv = x @ Wqkv_w + b
  gemm_mfma<0><<<dim3(24, 16), 256, 0, stream>>>(xb, wt_buf, Wqkv_b, qkv, 2048, 3072, 1024);
  // 2. softmax branch
  attn_mfma<<<dim3(512), 256, 0, stream>>>(qkv, ysm);
  // 3. STP branch
  stp_local<<<dim3(32, 16), 256, 0, stream>>>(qkv, Lam, Gam, states);
  stp_scan<<<dim3(256), 256, 0, stream>>>(Lam, states);
  stp_out<<<dim3(32, 16), 256, 0, stream>>>(qkv, Lam, Gam, W_st, states, ystp);
  // 4. gate
  transpose_conv<<<dim3(16, 32), 256, 0, stream>>>(gw1, wt_buf, 1024, 512);
  gemm_mfma<1><<<dim3(4, 16), 256, 0, stream>>>(xb, wt_buf, gb1, g, 2048, 512, 1024);
  gate2_kernel<<<dim3(128), 256, 0, stream>>>(g, gw2, gb2, alpha);
  // 5. combine -> bf16 (overlays states, which is dead now)
  combine_kernel<<<dim3(8192), 256, 0, stream>>>(ysm, ystp, alpha, ycb);
  // 6. out projection -> fp32 d_out
  transpose_conv<<<dim3(32, 32), 256, 0, stream>>>(out_w, wt_buf, 1024, 1024);
  gemm_mfma<0><<<dim3(8, 16), 256, 0, stream>>>(ycb, wt_buf, out_b, (float*)d_out, 2048, 1024, 1024);
}

// Round 5
// 306.971 us; speedup vs baseline: 4.0898x; 1.2369x over previous
//
#include <hip/hip_runtime.h>
#include <hip/hip_bf16.h>

#define L_SEQ 2048
#define DMODEL 1024
#define NHEAD 16
#define DHEAD 64
#define D3 3072

typedef __attribute__((ext_vector_type(8))) short s8v;   // 8 bf16 (4 VGPRs)
typedef __attribute__((ext_vector_type(4))) float f4v;   // MFMA acc
typedef unsigned int u32;

__device__ __forceinline__ short f2bf(float f) {
  __hip_bfloat16 h = __float2bfloat16(f);
  return *reinterpret_cast<short*>(&h);
}
__device__ __forceinline__ int pack2bf(float lo, float hi) {
  return (int)(((unsigned)(unsigned short)f2bf(hi) << 16) |
               (unsigned)(unsigned short)f2bf(lo));
}

// ---------------- x -> bf16 (row-major) -------------------------------------
__global__ __launch_bounds__(256) void conv_x(const float* __restrict__ x,
                                              short* __restrict__ xb)
{
  int i = (blockIdx.x * 256 + threadIdx.x) * 4;
  float4 v = *(const float4*)(x + i);
  short4 o;
  o.x = f2bf(v.x); o.y = f2bf(v.y); o.z = f2bf(v.z); o.w = f2bf(v.w);
  *(short4*)(xb + i) = o;
}

// ---------------- W (K x N fp32) -> W^T (N x K bf16) ------------------------
__global__ __launch_bounds__(256) void transpose_conv(const float* __restrict__ W,
    short* __restrict__ Wt, int K, int N)
{
  __shared__ float T[32][33];
  int bx = blockIdx.x, by = blockIdx.y;      // bx: N/32, by: K/32
  int col = threadIdx.x & 31, rb = threadIdx.x >> 5;
  #pragma unroll
  for (int it = 0; it < 4; ++it) {
    int r = it * 8 + rb;
    T[r][col] = W[(size_t)(by * 32 + r) * N + bx * 32 + col];
  }
  __syncthreads();
  #pragma unroll
  for (int it = 0; it < 4; ++it) {
    int r = it * 8 + rb;
    Wt[(size_t)(bx * 32 + r) * K + by * 32 + col] = f2bf(T[col][r]);
  }
}

// ---------------- qkv fp32 -> Qb/Kb (H,L,64) bf16, Vtb (H,64,L) bf16 --------
__global__ __launch_bounds__(256) void conv_qkv(const float* __restrict__ qkv,
    short* __restrict__ Qb, short* __restrict__ Kb, short* __restrict__ Vtb)
{
  int kb = blockIdx.x, h = blockIdx.y;
  int tid = threadIdx.x;
  __shared__ float Vs[64][65];
  for (int idx = tid; idx < 2048; idx += 256) {
    int key = idx >> 5, e2 = idx & 31;
    size_t base = (size_t)(kb * 64 + key) * D3 + h * 64 + e2 * 2;
    float2 qv = *(const float2*)(qkv + base);
    float2 kv = *(const float2*)(qkv + base + 1024);
    float2 vv = *(const float2*)(qkv + base + 2048);
    size_t o = ((size_t)h * 2048 + kb * 64 + key) * 64 + e2 * 2;
    *(int*)&Qb[o] = pack2bf(qv.x, qv.y);
    *(int*)&Kb[o] = pack2bf(kv.x, kv.y);
    Vs[key][e2 * 2] = vv.x; Vs[key][e2 * 2 + 1] = vv.y;
  }
  __syncthreads();
  for (int idx = tid; idx < 2048; idx += 256) {
    int dim = idx >> 5, k2 = idx & 31;
    *(int*)&Vtb[((size_t)h * 64 + dim) * 2048 + kb * 64 + k2 * 2] =
        pack2bf(Vs[k2 * 2][dim], Vs[k2 * 2 + 1][dim]);
  }
}

// ---------------- bf16 MFMA GEMM (m97 structure) ----------------------------
template<int EPI>
__global__ __launch_bounds__(256) void gemm_mfma(
    const short* __restrict__ A, const short* __restrict__ Bt,
    const float* __restrict__ bias, float* __restrict__ C,
    int M, int N, int K)
{
  __shared__ __align__(16) short As[128 * 32];
  __shared__ __align__(16) short Bs[128 * 32];
  const int tid = threadIdx.x;
  const int w = tid >> 6, lane = tid & 63;
  const int quad = lane >> 4, c = lane & 15;
  const int m0 = blockIdx.y * 128, n0 = blockIdx.x * 128;
  const int wm = (w & 1) * 64, wn = (w >> 1) * 64;
  f4v acc[4][4] = {};

  int off0 = (w * 2) * 1024 + lane * 16;
  int row0s = off0 >> 6, colh0 = (off0 & 63) >> 1;
  int off1 = off0 + 1024;
  int row1s = off1 >> 6, colh1 = (off1 & 63) >> 1;

  for (int k0 = 0; k0 < K; k0 += 32) {
    const short* gA0 = A + (size_t)(m0 + row0s) * K + k0 + colh0;
    const short* gA1 = A + (size_t)(m0 + row1s) * K + k0 + colh1;
    const short* gB0 = Bt + (size_t)(n0 + row0s) * K + k0 + colh0;
    const short* gB1 = Bt + (size_t)(n0 + row1s) * K + k0 + colh1;
    __builtin_amdgcn_global_load_lds(
        (const __attribute__((address_space(1))) u32*)gA0,
        (__attribute__((address_space(3))) u32*)(As + (w * 2) * 512), 16, 0, 0);
    __builtin_amdgcn_global_load_lds(
        (const __attribute__((address_space(1))) u32*)gA1,
        (__attribute__((address_space(3))) u32*)(As + (w * 2 + 1) * 512), 16, 0, 0);
    __builtin_amdgcn_global_load_lds(
        (const __attribute__((address_space(1))) u32*)gB0,
        (__attribute__((address_space(3))) u32*)(Bs + (w * 2) * 512), 16, 0, 0);
    __builtin_amdgcn_global_load_lds(
        (const __attribute__((address_space(1))) u32*)gB1,
        (__attribute__((address_space(3))) u32*)(Bs + (w * 2 + 1) * 512), 16, 0, 0);
    __syncthreads();
    s8v af[4], bf[4];
    #pragma unroll
    for (int mt = 0; mt < 4; ++mt)
      af[mt] = *(s8v*)&As[(wm + mt * 16 + c) * 32 + quad * 8];
    #pragma unroll
    for (int nt = 0; nt < 4; ++nt)
      bf[nt] = *(s8v*)&Bs[(wn + nt * 16 + c) * 32 + quad * 8];
    #pragma unroll
    for (int mt = 0; mt < 4; ++mt)
      #pragma unroll
      for (int nt = 0; nt < 4; ++nt)
        acc[mt][nt] = __builtin_amdgcn_mfma_f32_16x16x32_bf16(
            af[mt], bf[nt], acc[mt][nt], 0, 0, 0);
    __syncthreads();
  }
  #pragma unroll
  for (int mt = 0; mt < 4; ++mt)
    #pragma unroll
    for (int r = 0; r < 4; ++r) {
      int m = m0 + wm + mt * 16 + quad * 4 + r;
      #pragma unroll
      for (int nt = 0; nt < 4; ++nt) {
        int n = n0 + wn + nt * 16 + c;
        float v = acc[mt][nt][r] + bias[n];
        if (EPI == 1) v = 0.5f * v * (1.0f + erff(v * 0.70710678118654752f));
        C[(size_t)m * N + n] = v;
      }
    }
}

// ---------------- bf16 MFMA flash attention v2 ------------------------------
// Pre-converted bf16 inputs; register-prefetched staging (1 tile ahead).
__global__ __launch_bounds__(256) void attn_mfma(
    const short* __restrict__ Qb, const short* __restrict__ Kb,
    const short* __restrict__ Vtb, float* __restrict__ ysm)
{
  const int bid = blockIdx.x;
  const int h  = bid & 15;
  const int qt = bid >> 4;
  const int q0 = qt * 64;
  const int nt = qt + 1;
  const int tid = threadIdx.x;
  const int w = tid >> 6, lane = tid & 63;
  const int quad = lane >> 4, c = lane & 15;

  __shared__ __align__(16) char smem[27648];
  short* Ks = (short*)smem;          // [key][dim]  stride 72
  short* Vt = Ks + 4608;             // [dim][key]  stride 72
  short* Ps = Vt + 4608;             // [wave][16][72]
  float* Ob = (float*)smem;          // [64][66] overlay

  const int qrow = q0 + w * 16 + c;
  s8v qf[2];
  qf[0] = *(const s8v*)(Qb + ((size_t)h * 2048 + qrow) * 64 + quad * 8);
  qf[1] = *(const s8v*)(Qb + ((size_t)h * 2048 + qrow) * 64 + 32 + quad * 8);

  const int srow = tid >> 3, sc = (tid & 7) * 8;   // staging: row, col-start
  int4 pk0, pk1, pv0, pv1;
  auto load_tile = [&](int t0) {
    const short* kbase = Kb + ((size_t)h * 2048 + t0 * 64) * 64;
    const short* vbase = Vtb + (size_t)h * 64 * 2048 + t0 * 64;
    pk0 = *(const int4*)(kbase + (size_t)srow * 64 + sc);
    pk1 = *(const int4*)(kbase + (size_t)(srow + 32) * 64 + sc);
    pv0 = *(const int4*)(vbase + (size_t)srow * 2048 + sc);
    pv1 = *(const int4*)(vbase + (size_t)(srow + 32) * 2048 + sc);
  };
  load_tile(0);

  f4v o_acc[4] = {};
  float m = -1e30f, l = 0.f;

  for (int t0 = 0; t0 < nt; ++t0) {
    __syncthreads();                       // prior compute done: LDS reusable
    *(int4*)&Ks[srow * 72 + sc] = pk0;
    *(int4*)&Ks[(srow + 32) * 72 + sc] = pk1;
    *(int4*)&Vt[srow * 72 + sc] = pv0;
    *(int4*)&Vt[(srow + 32) * 72 + sc] = pv1;
    __syncthreads();
    if (t0 + 1 < nt) load_tile(t0 + 1);    // async prefetch into regs

    // S^T = K·Q^T
    f4v s_acc[4] = {};
    #pragma unroll
    for (int kt = 0; kt < 4; ++kt) {
      #pragma unroll
      for (int kc = 0; kc < 2; ++kc) {
        s8v kf = *(s8v*)&Ks[(kt * 16 + c) * 72 + kc * 32 + quad * 8];
        s_acc[kt] = __builtin_amdgcn_mfma_f32_16x16x32_bf16(kf, qf[kc], s_acc[kt], 0, 0, 0);
      }
    }
    float sv[4][4];
    bool full = (t0 * 64 + 63) <= (q0 + w * 16);
    #pragma unroll
    for (int kt = 0; kt < 4; ++kt)
      #pragma unroll
      for (int r = 0; r < 4; ++r) {
        float s = s_acc[kt][r] * 0.125f;
        if (!full) {
          int key = t0 * 64 + kt * 16 + quad * 4 + r;
          s = (key <= qrow) ? s : -1e30f;
        }
        sv[kt][r] = s;
      }
    float mloc = -1e30f;
    #pragma unroll
    for (int kt = 0; kt < 4; ++kt)
      #pragma unroll
      for (int r = 0; r < 4; ++r) mloc = fmaxf(mloc, sv[kt][r]);
    mloc = fmaxf(mloc, __shfl_xor(mloc, 16));
    mloc = fmaxf(mloc, __shfl_xor(mloc, 32));
    float mnew = fmaxf(m, mloc);
    float alpha = __expf(m - mnew);
    m = mnew;
    float p[4][4], ls = 0.f;
    #pragma unroll
    for (int kt = 0; kt < 4; ++kt)
      #pragma unroll
      for (int r = 0; r < 4; ++r) { p[kt][r] = __expf(sv[kt][r] - mnew); ls += p[kt][r]; }
    ls += __shfl_xor(ls, 16);
    ls += __shfl_xor(ls, 32);
    l = l * alpha + ls;
    #pragma unroll
    for (int mt = 0; mt < 4; ++mt)
      #pragma unroll
      for (int r = 0; r < 4; ++r) o_acc[mt][r] *= alpha;
    short* Pw = Ps + w * 1152;
    #pragma unroll
    for (int kt = 0; kt < 4; ++kt) {
      *(int*)&Pw[c * 72 + kt * 16 + quad * 4]     = pack2bf(p[kt][0], p[kt][1]);
      *(int*)&Pw[c * 72 + kt * 16 + quad * 4 + 2] = pack2bf(p[kt][2], p[kt][3]);
    }
    #pragma unroll
    for (int kc2 = 0; kc2 < 2; ++kc2) {
      s8v pf = *(s8v*)&Pw[c * 72 + kc2 * 32 + quad * 8];
      #pragma unroll
      for (int mt = 0; mt < 4; ++mt) {
        s8v vf = *(s8v*)&Vt[(mt * 16 + c) * 72 + kc2 * 32 + quad * 8];
        o_acc[mt] = __builtin_amdgcn_mfma_f32_16x16x32_bf16(vf, pf, o_acc[mt], 0, 0, 0);
      }
    }
  }

  float rinv = 1.f / l;
  __syncthreads();
  #pragma unroll
  for (int mt = 0; mt < 4; ++mt)
    #pragma unroll
    for (int r = 0; r < 4; ++r)
      Ob[(w * 16 + c) * 66 + mt * 16 + quad * 4 + r] = o_acc[mt][r] * rinv;
  __syncthreads();
  for (int i = tid; i < 4096; i += 256) {
    int q = i >> 6, e = i & 63;
    ysm[((size_t)h * L_SEQ + q0 + q) * 64 + e] = Ob[q * 66 + e];
  }
}

// ---------------- STP branch (unchanged) ------------------------------------
__global__ __launch_bounds__(256) void stp_local(const float* __restrict__ qkv,
    const float* __restrict__ Lam, const float* __restrict__ Gam,
    float* __restrict__ states)
{
  int c = blockIdx.x, h = blockIdx.y;
  int tid = threadIdx.x;
  int i = tid >> 2, j0 = (tid & 3) * 16;
  __shared__ float Kc[64][64];
  __shared__ float Vc[64][64];
  for (int idx = tid; idx < 64 * 64; idx += 256) {
    int t = idx >> 6, e = idx & 63;
    size_t base = (size_t)(c * 64 + t) * D3 + h * 64 + e;
    Kc[t][e] = qkv[base + 1024] * 0.125f;
    Vc[t][e] = qkv[base + 2048];
  }
  float r[16], g[16], s[16];
  #pragma unroll
  for (int e = 0; e < 16; ++e) {
    int idx = h * 4096 + i * 64 + j0 + e;
    float lam = Lam[idx];
    r[e] = 1.f / (1.f + expf(lam));
    g[e] = Gam[idx];
    s[e] = 0.f;
  }
  __syncthreads();
  for (int t = 0; t < 64; ++t) {
    float v = Vc[t][i];
    #pragma unroll
    for (int e = 0; e < 16; ++e)
      s[e] = r[e] * s[e] + g[e] * (v * Kc[t][j0 + e]);
  }
  #pragma unroll
  for (int e = 0; e < 16; ++e)
    states[((size_t)h * 32 + c) * 4096 + i * 64 + j0 + e] = s[e];
}

__global__ __launch_bounds__(256) void stp_scan(const float* __restrict__ Lam,
                                                float* __restrict__ states)
{
  int gid = blockIdx.x * 256 + threadIdx.x;
  float lam = Lam[gid];
  float r = 1.f / (1.f + expf(lam));
  float r64 = r;
  #pragma unroll
  for (int q = 0; q < 6; ++q) r64 *= r64;
  int h = gid >> 12, low = gid & 4095;
  float acc = 0.f;
  for (int c = 0; c < 32; ++c) {
    size_t idx = ((size_t)h * 32 + c) * 4096 + low;
    float dloc = states[idx];
    states[idx] = acc;
    acc = r64 * acc + dloc;
  }
}

__global__ __launch_bounds__(256) void stp_out(const float* __restrict__ qkv,
    const float* __restrict__ Lam, const float* __restrict__ Gam,
    const float* __restrict__ Wst, const float* __restrict__ states,
    float* __restrict__ ystp)
{
  int c = blockIdx.x, h = blockIdx.y;
  int tid = threadIdx.x;
  int i = tid >> 2, j0 = (tid & 3) * 16;
  __shared__ float Kc[64][64];
  __shared__ float Vc[64][64];
  __shared__ float Qc[64][64];
  for (int idx = tid; idx < 64 * 64; idx += 256) {
    int t = idx >> 6, e = idx & 63;
    size_t base = (size_t)(c * 64 + t) * D3 + h * 64 + e;
    Qc[t][e] = qkv[base];
    Kc[t][e] = qkv[base + 1024] * 0.125f;
    Vc[t][e] = qkv[base + 2048];
  }
  float r[16], g[16], s[16], w[16];
  #pragma unroll
  for (int e = 0; e < 16; ++e) {
    int idx = h * 4096 + i * 64 + j0 + e;
    float lam = Lam[idx];
    r[e] = 1.f / (1.f + expf(lam));
    g[e] = Gam[idx];
    w[e] = Wst[idx];
    s[e] = states[((size_t)h * 32 + c) * 4096 + i * 64 + j0 + e];
  }
  __syncthreads();
  for (int t = 0; t < 64; ++t) {
    float v = Vc[t][i];
    float y = 0.f;
    #pragma unroll
    for (int e = 0; e < 16; ++e) {
      s[e] = r[e] * s[e] + g[e] * (v * Kc[t][j0 + e]);
      y += (w[e] + s[e]) * Qc[t][j0 + e];
    }
    y += __shfl_xor(y, 1);
    y += __shfl_xor(y, 2);
    if ((tid & 3) == 0)
      ystp[((size_t)h * L_SEQ + c * 64 + t) * 64 + i] = y;
  }
}

// ---------------- gate tail --------------------------------------------------
__global__ __launch_bounds__(256) void gate2_kernel(const float* __restrict__ g,
    const float* __restrict__ w2, const float* __restrict__ b2,
    float* __restrict__ alpha)
{
  int gid = blockIdx.x * 256 + threadIdx.x;
  int l = gid >> 4, h = gid & 15;
  float acc = b2[h];
  const float* grow = g + (size_t)l * 512;
  for (int c = 0; c < 512; ++c) acc += grow[c] * w2[c * 16 + h];
  alpha[gid] = 1.f / (1.f + expf(-acc));
}

// ---------------- combine + transpose -> bf16 (L, D) ------------------------
__global__ __launch_bounds__(256) void combine_kernel(const float* __restrict__ ysm,
    const float* __restrict__ ystp, const float* __restrict__ alpha,
    short* __restrict__ ycb)
{
  int gid = blockIdx.x * 256 + threadIdx.x;
  int l = gid >> 10, cidx = gid & 1023;
  int h = cidx >> 6, e = cidx & 63;
  float a = alpha[l * 16 + h];
  size_t src = ((size_t)h * L_SEQ + l) * 64 + e;
  ycb[gid] = f2bf(a * ysm[src] + (1.f - a) * ystp[src]);
}

extern "C" void kernel_launch(void* const* d_in, const int* in_sizes, int n_in,
                              void* d_out, int out_size, void* d_ws, size_t ws_size,
                              hipStream_t stream) {
  (void)in_sizes; (void)n_in; (void)out_size; (void)ws_size;
  const float* x      = (const float*)d_in[0];
  const float* Wqkv_w = (const float*)d_in[1];
  const float* Wqkv_b = (const float*)d_in[2];
  const float* out_w  = (const float*)d_in[3];
  const float* out_b  = (const float*)d_in[4];
  const float* W_st   = (const float*)d_in[5];
  const float* Lam    = (const float*)d_in[6];
  const float* Gam    = (const float*)d_in[7];
  const float* gw1    = (const float*)d_in[8];
  const float* gb1    = (const float*)d_in[9];
  const float* gw2    = (const float*)d_in[10];
  const float* gb2    = (const float*)d_in[11];

  float* ws     = (float*)d_ws;
  float* qkv    = ws;                       //  0        .. 6291456
  float* ysm    = ws + 6291456;             //  8.4 MB
  float* ystp   = ws + 8388608;
  float* states = ws + 10485760;
  float* ovl    = ws + 12582912;            // overlay span (14.7 MB)
  float* g      = ovl;                      //  g: ovl .. +1048576   (phase 1)
  short* xb     = (short*)(ovl + 1048576);  //  xb (phase 1)
  short* wt_buf = (short*)(ovl + 2097152);  //  weights^T (phases 1 & 3)
  float* alpha  = ws + 16252928;            //  .. 16285696 (65.1 MB total)
  short* Qb     = (short*)ovl;              //  phase 2: overwrites g
  short* Kb     = (short*)(ovl + 1048576);  //  phase 2: overwrites xb
  short* Vtb    = (short*)(ovl + 2097152);  //  phase 2: overwrites wt_buf head
  short* ycb    = (short*)states;           //  states dead after stp_out

  // phase 1: projections off x (uses xb, wt_buf, g)
  conv_x<<<dim3(2048), 256, 0, stream>>>(x, xb);
  transpose_conv<<<dim3(96, 32), 256, 0, stream>>>(Wqkv_w, wt_buf, 1024, 3072);
  gemm_mfma<0><<<dim3(24, 16), 256, 0, stream>>>(xb, wt_buf, Wqkv_b, qkv, 2048, 3072, 1024);
  transpose_conv<<<dim3(16, 32), 256, 0, stream>>>(gw1, wt_buf, 1024, 512);
  gemm_mfma<1><<<dim3(4, 16), 256, 0, stream>>>(xb, wt_buf, gb1, g, 2048, 512, 1024);
  gate2_kernel<<<dim3(128), 256, 0, stream>>>(g, gw2, gb2, alpha);
  // STP branch (fp32 qkv)
  stp_local<<<dim3(32, 16), 256, 0, stream>>>(qkv, Lam, Gam, states);
  stp_scan<<<dim3(256), 256, 0, stream>>>(Lam, states);
  stp_out<<<dim3(32, 16), 256, 0, stream>>>(qkv, Lam, Gam, W_st, states, ystp);
  // phase 2: attention on bf16 layouts (overwrites g/xb/wt_buf — all dead)
  conv_qkv<<<dim3(32, 16), 256, 0, stream>>>(qkv, Qb, Kb, Vtb);
  attn_mfma<<<dim3(512), 256, 0, stream>>>(Qb, Kb, Vtb, ysm);
  // combine -> bf16 (overlays states)
  combine_kernel<<<dim3(8192), 256, 0, stream>>>(ysm, ystp, alpha, ycb);
  // phase 3: out projection (wt_buf region free again after attention)
  transpose_conv<<<dim3(32, 32), 256, 0, stream>>>(out_w, wt_buf, 1024, 1024);
  gemm_mfma<0><<<dim3(8, 16), 256, 0, stream>>>(ycb, wt_buf, out_b, (float*)d_out, 2048, 1024, 1024);
}

// Round 6
// 275.821 us; speedup vs baseline: 4.5517x; 1.1129x over previous
//
#include <hip/hip_runtime.h>
#include <hip/hip_bf16.h>

#define L_SEQ 2048
#define DMODEL 1024
#define NHEAD 16
#define DHEAD 64
#define D3 3072

typedef __attribute__((ext_vector_type(8))) short s8v;   // 8 bf16 (4 VGPRs)
typedef __attribute__((ext_vector_type(4))) float f4v;   // MFMA acc
typedef unsigned int u32;
#define AS1 __attribute__((address_space(1)))
#define AS3 __attribute__((address_space(3)))

__device__ __forceinline__ short f2bf(float f) {
  __hip_bfloat16 h = __float2bfloat16(f);
  return *reinterpret_cast<short*>(&h);
}
__device__ __forceinline__ int pack2bf(float lo, float hi) {
  return (int)(((unsigned)(unsigned short)f2bf(hi) << 16) |
               (unsigned)(unsigned short)f2bf(lo));
}

// ---------------- x -> bf16 (row-major) -------------------------------------
__global__ __launch_bounds__(256) void conv_x(const float* __restrict__ x,
                                              short* __restrict__ xb)
{
  int i = (blockIdx.x * 256 + threadIdx.x) * 4;
  float4 v = *(const float4*)(x + i);
  short4 o;
  o.x = f2bf(v.x); o.y = f2bf(v.y); o.z = f2bf(v.z); o.w = f2bf(v.w);
  *(short4*)(xb + i) = o;
}

// ---------------- W (K x N fp32) -> W^T (N x K bf16) ------------------------
__global__ __launch_bounds__(256) void transpose_conv(const float* __restrict__ W,
    short* __restrict__ Wt, int K, int N)
{
  __shared__ float T[32][33];
  int bx = blockIdx.x, by = blockIdx.y;      // bx: N/32, by: K/32
  int col = threadIdx.x & 31, rb = threadIdx.x >> 5;
  #pragma unroll
  for (int it = 0; it < 4; ++it) {
    int r = it * 8 + rb;
    T[r][col] = W[(size_t)(by * 32 + r) * N + bx * 32 + col];
  }
  __syncthreads();
  #pragma unroll
  for (int it = 0; it < 4; ++it) {
    int r = it * 8 + rb;
    Wt[(size_t)(bx * 32 + r) * K + by * 32 + col] = f2bf(T[col][r]);
  }
}

// ---------------- qkv fp32 -> Qb/Kb (H,L,64) bf16, Vtb (H,64,L) bf16 --------
__global__ __launch_bounds__(256) void conv_qkv(const float* __restrict__ qkv,
    short* __restrict__ Qb, short* __restrict__ Kb, short* __restrict__ Vtb)
{
  int kb = blockIdx.x, h = blockIdx.y;
  int tid = threadIdx.x;
  __shared__ float Vs[64][65];
  for (int idx = tid; idx < 2048; idx += 256) {
    int key = idx >> 5, e2 = idx & 31;
    size_t base = (size_t)(kb * 64 + key) * D3 + h * 64 + e2 * 2;
    float2 qv = *(const float2*)(qkv + base);
    float2 kv = *(const float2*)(qkv + base + 1024);
    float2 vv = *(const float2*)(qkv + base + 2048);
    size_t o = ((size_t)h * 2048 + kb * 64 + key) * 64 + e2 * 2;
    *(int*)&Qb[o] = pack2bf(qv.x, qv.y);
    *(int*)&Kb[o] = pack2bf(kv.x, kv.y);
    Vs[key][e2 * 2] = vv.x; Vs[key][e2 * 2 + 1] = vv.y;
  }
  __syncthreads();
  for (int idx = tid; idx < 2048; idx += 256) {
    int dim = idx >> 5, k2 = idx & 31;
    *(int*)&Vtb[((size_t)h * 64 + dim) * 2048 + kb * 64 + k2 * 2] =
        pack2bf(Vs[k2 * 2][dim], Vs[k2 * 2 + 1][dim]);
  }
}

// ---------------- bf16 MFMA GEMM, double-buffered prefetch ------------------
// MODE 0: C = A@B + bias (fp32 out, row stride N)
// MODE 2: fused qkv+gate: n<3072 -> qkv(+bias); n>=3072 -> GELU(.+bias2) -> bf16 C2
template<int BM, int BN, int MODE>
__global__ __launch_bounds__(256) void gemm_mfma(
    const short* __restrict__ A, const short* __restrict__ Bt,
    const float* __restrict__ bias, const float* __restrict__ bias2,
    float* __restrict__ C, short* __restrict__ C2,
    int M, int N, int K)
{
  constexpr int LA = BM / 64, LB = BN / 64;      // 16B loads/thread/tile
  constexpr int WM = BM / 2, WN = BN / 2;
  constexpr int MT = WM / 16, NT = WN / 16;
  __shared__ __align__(16) short As[2][BM * 32];
  __shared__ __align__(16) short Bs[2][BN * 32];
  const int tid = threadIdx.x;
  const int w = tid >> 6, lane = tid & 63;
  const int quad = lane >> 4, c = lane & 15;
  const int m0 = blockIdx.y * BM, n0 = blockIdx.x * BN;
  const int wm = (w & 1) * WM, wn = (w >> 1) * WN;
  f4v acc[MT][NT] = {};

  auto stage = [&](int buf, int k0) {
    #pragma unroll
    for (int it = 0; it < LA; ++it) {
      int off = (it * 256 + tid) * 16;           // bytes within tile
      int row = off >> 6, colh = (off & 63) >> 1;
      __builtin_amdgcn_global_load_lds(
          (const AS1 u32*)(A + (size_t)(m0 + row) * K + k0 + colh),
          (AS3 u32*)(&As[buf][0] + (off >> 1)), 16, 0, 0);
    }
    #pragma unroll
    for (int it = 0; it < LB; ++it) {
      int off = (it * 256 + tid) * 16;
      int row = off >> 6, colh = (off & 63) >> 1;
      __builtin_amdgcn_global_load_lds(
          (const AS1 u32*)(Bt + (size_t)(n0 + row) * K + k0 + colh),
          (AS3 u32*)(&Bs[buf][0] + (off >> 1)), 16, 0, 0);
    }
  };
  stage(0, 0);
  int cur = 0;
  for (int k0 = 0; k0 < K; k0 += 32) {
    __syncthreads();                 // drains cur's loads; all waves done w/ cur^1
    if (k0 + 32 < K) stage(cur ^ 1, k0 + 32);   // prefetch overlaps compute
    s8v af[MT], bf[NT];
    #pragma unroll
    for (int mt = 0; mt < MT; ++mt)
      af[mt] = *(s8v*)&As[cur][(wm + mt * 16 + c) * 32 + quad * 8];
    #pragma unroll
    for (int nt = 0; nt < NT; ++nt)
      bf[nt] = *(s8v*)&Bs[cur][(wn + nt * 16 + c) * 32 + quad * 8];
    #pragma unroll
    for (int mt = 0; mt < MT; ++mt)
      #pragma unroll
      for (int nt = 0; nt < NT; ++nt)
        acc[mt][nt] = __builtin_amdgcn_mfma_f32_16x16x32_bf16(
            af[mt], bf[nt], acc[mt][nt], 0, 0, 0);
    cur ^= 1;
  }
  #pragma unroll
  for (int mt = 0; mt < MT; ++mt)
    #pragma unroll
    for (int r = 0; r < 4; ++r) {
      int m = m0 + wm + mt * 16 + quad * 4 + r;
      #pragma unroll
      for (int nt = 0; nt < NT; ++nt) {
        int n = n0 + wn + nt * 16 + c;
        float v = acc[mt][nt][r];
        if (MODE == 0) {
          C[(size_t)m * N + n] = v + bias[n];
        } else {
          if (n < 3072) {
            C[(size_t)m * 3072 + n] = v + bias[n];
          } else {
            float t = v + bias2[n - 3072];
            t = 0.5f * t * (1.0f + erff(t * 0.70710678118654752f));
            C2[(size_t)m * 512 + (n - 3072)] = f2bf(t);
          }
        }
      }
    }
}

// ---------------- bf16 MFMA flash attention (register-prefetch) -------------
__global__ __launch_bounds__(256) void attn_mfma(
    const short* __restrict__ Qb, const short* __restrict__ Kb,
    const short* __restrict__ Vtb, float* __restrict__ ysm)
{
  const int bid = blockIdx.x;
  const int h  = bid & 15;
  const int qt = bid >> 4;
  const int q0 = qt * 64;
  const int nt = qt + 1;
  const int tid = threadIdx.x;
  const int w = tid >> 6, lane = tid & 63;
  const int quad = lane >> 4, c = lane & 15;

  __shared__ __align__(16) char smem[27648];
  short* Ks = (short*)smem;          // [key][dim]  stride 72
  short* Vt = Ks + 4608;             // [dim][key]  stride 72
  short* Ps = Vt + 4608;             // [wave][16][72]
  float* Ob = (float*)smem;          // [64][66] overlay

  const int qrow = q0 + w * 16 + c;
  s8v qf[2];
  qf[0] = *(const s8v*)(Qb + ((size_t)h * 2048 + qrow) * 64 + quad * 8);
  qf[1] = *(const s8v*)(Qb + ((size_t)h * 2048 + qrow) * 64 + 32 + quad * 8);

  const int srow = tid >> 3, sc = (tid & 7) * 8;
  int4 pk0, pk1, pv0, pv1;
  auto load_tile = [&](int t0) {
    const short* kbase = Kb + ((size_t)h * 2048 + t0 * 64) * 64;
    const short* vbase = Vtb + (size_t)h * 64 * 2048 + t0 * 64;
    pk0 = *(const int4*)(kbase + (size_t)srow * 64 + sc);
    pk1 = *(const int4*)(kbase + (size_t)(srow + 32) * 64 + sc);
    pv0 = *(const int4*)(vbase + (size_t)srow * 2048 + sc);
    pv1 = *(const int4*)(vbase + (size_t)(srow + 32) * 2048 + sc);
  };
  load_tile(0);

  f4v o_acc[4] = {};
  float m = -1e30f, l = 0.f;

  for (int t0 = 0; t0 < nt; ++t0) {
    __syncthreads();
    *(int4*)&Ks[srow * 72 + sc] = pk0;
    *(int4*)&Ks[(srow + 32) * 72 + sc] = pk1;
    *(int4*)&Vt[srow * 72 + sc] = pv0;
    *(int4*)&Vt[(srow + 32) * 72 + sc] = pv1;
    __syncthreads();
    if (t0 + 1 < nt) load_tile(t0 + 1);

    f4v s_acc[4] = {};
    #pragma unroll
    for (int kt = 0; kt < 4; ++kt) {
      #pragma unroll
      for (int kc = 0; kc < 2; ++kc) {
        s8v kf = *(s8v*)&Ks[(kt * 16 + c) * 72 + kc * 32 + quad * 8];
        s_acc[kt] = __builtin_amdgcn_mfma_f32_16x16x32_bf16(kf, qf[kc], s_acc[kt], 0, 0, 0);
      }
    }
    float sv[4][4];
    bool full = (t0 * 64 + 63) <= (q0 + w * 16);
    #pragma unroll
    for (int kt = 0; kt < 4; ++kt)
      #pragma unroll
      for (int r = 0; r < 4; ++r) {
        float s = s_acc[kt][r] * 0.125f;
        if (!full) {
          int key = t0 * 64 + kt * 16 + quad * 4 + r;
          s = (key <= qrow) ? s : -1e30f;
        }
        sv[kt][r] = s;
      }
    float mloc = -1e30f;
    #pragma unroll
    for (int kt = 0; kt < 4; ++kt)
      #pragma unroll
      for (int r = 0; r < 4; ++r) mloc = fmaxf(mloc, sv[kt][r]);
    mloc = fmaxf(mloc, __shfl_xor(mloc, 16));
    mloc = fmaxf(mloc, __shfl_xor(mloc, 32));
    float mnew = fmaxf(m, mloc);
    float alpha = __expf(m - mnew);
    m = mnew;
    float p[4][4], ls = 0.f;
    #pragma unroll
    for (int kt = 0; kt < 4; ++kt)
      #pragma unroll
      for (int r = 0; r < 4; ++r) { p[kt][r] = __expf(sv[kt][r] - mnew); ls += p[kt][r]; }
    ls += __shfl_xor(ls, 16);
    ls += __shfl_xor(ls, 32);
    l = l * alpha + ls;
    #pragma unroll
    for (int mt = 0; mt < 4; ++mt)
      #pragma unroll
      for (int r = 0; r < 4; ++r) o_acc[mt][r] *= alpha;
    short* Pw = Ps + w * 1152;
    #pragma unroll
    for (int kt = 0; kt < 4; ++kt) {
      *(int*)&Pw[c * 72 + kt * 16 + quad * 4]     = pack2bf(p[kt][0], p[kt][1]);
      *(int*)&Pw[c * 72 + kt * 16 + quad * 4 + 2] = pack2bf(p[kt][2], p[kt][3]);
    }
    #pragma unroll
    for (int kc2 = 0; kc2 < 2; ++kc2) {
      s8v pf = *(s8v*)&Pw[c * 72 + kc2 * 32 + quad * 8];
      #pragma unroll
      for (int mt = 0; mt < 4; ++mt) {
        s8v vf = *(s8v*)&Vt[(mt * 16 + c) * 72 + kc2 * 32 + quad * 8];
        o_acc[mt] = __builtin_amdgcn_mfma_f32_16x16x32_bf16(vf, pf, o_acc[mt], 0, 0, 0);
      }
    }
  }

  float rinv = 1.f / l;
  __syncthreads();
  #pragma unroll
  for (int mt = 0; mt < 4; ++mt)
    #pragma unroll
    for (int r = 0; r < 4; ++r)
      Ob[(w * 16 + c) * 66 + mt * 16 + quad * 4 + r] = o_acc[mt][r] * rinv;
  __syncthreads();
  for (int i = tid; i < 4096; i += 256) {
    int q = i >> 6, e = i & 63;
    ysm[((size_t)h * L_SEQ + q0 + q) * 64 + e] = Ob[q * 66 + e];
  }
}

// ---------------- STP branch ------------------------------------------------
__global__ __launch_bounds__(256) void stp_local(const float* __restrict__ qkv,
    const float* __restrict__ Lam, const float* __restrict__ Gam,
    float* __restrict__ states)
{
  int c = blockIdx.x, h = blockIdx.y;
  int tid = threadIdx.x;
  int i = tid >> 2, j0 = (tid & 3) * 16;
  __shared__ float Kc[64][64];
  __shared__ float Vc[64][64];
  for (int idx = tid; idx < 64 * 64; idx += 256) {
    int t = idx >> 6, e = idx & 63;
    size_t base = (size_t)(c * 64 + t) * D3 + h * 64 + e;
    Kc[t][e] = qkv[base + 1024] * 0.125f;
    Vc[t][e] = qkv[base + 2048];
  }
  float r[16], g[16], s[16];
  #pragma unroll
  for (int e = 0; e < 16; ++e) {
    int idx = h * 4096 + i * 64 + j0 + e;
    float lam = Lam[idx];
    r[e] = 1.f / (1.f + expf(lam));
    g[e] = Gam[idx];
    s[e] = 0.f;
  }
  __syncthreads();
  for (int t = 0; t < 64; ++t) {
    float v = Vc[t][i];
    #pragma unroll
    for (int e = 0; e < 16; ++e)
      s[e] = r[e] * s[e] + g[e] * (v * Kc[t][j0 + e]);
  }
  #pragma unroll
  for (int e = 0; e < 16; ++e)
    states[((size_t)h * 32 + c) * 4096 + i * 64 + j0 + e] = s[e];
}

__global__ __launch_bounds__(256) void stp_scan(const float* __restrict__ Lam,
                                                float* __restrict__ states)
{
  int gid = blockIdx.x * 256 + threadIdx.x;
  float lam = Lam[gid];
  float r = 1.f / (1.f + expf(lam));
  float r64 = r;
  #pragma unroll
  for (int q = 0; q < 6; ++q) r64 *= r64;
  int h = gid >> 12, low = gid & 4095;
  float acc = 0.f;
  for (int c = 0; c < 32; ++c) {
    size_t idx = ((size_t)h * 32 + c) * 4096 + low;
    float dloc = states[idx];
    states[idx] = acc;
    acc = r64 * acc + dloc;
  }
}

__global__ __launch_bounds__(256) void stp_out(const float* __restrict__ qkv,
    const float* __restrict__ Lam, const float* __restrict__ Gam,
    const float* __restrict__ Wst, const float* __restrict__ states,
    float* __restrict__ ystp)
{
  int c = blockIdx.x, h = blockIdx.y;
  int tid = threadIdx.x;
  int i = tid >> 2, j0 = (tid & 3) * 16;
  __shared__ float Kc[64][64];
  __shared__ float Vc[64][64];
  __shared__ float Qc[64][64];
  for (int idx = tid; idx < 64 * 64; idx += 256) {
    int t = idx >> 6, e = idx & 63;
    size_t base = (size_t)(c * 64 + t) * D3 + h * 64 + e;
    Qc[t][e] = qkv[base];
    Kc[t][e] = qkv[base + 1024] * 0.125f;
    Vc[t][e] = qkv[base + 2048];
  }
  float r[16], g[16], s[16], w[16];
  #pragma unroll
  for (int e = 0; e < 16; ++e) {
    int idx = h * 4096 + i * 64 + j0 + e;
    float lam = Lam[idx];
    r[e] = 1.f / (1.f + expf(lam));
    g[e] = Gam[idx];
    w[e] = Wst[idx];
    s[e] = states[((size_t)h * 32 + c) * 4096 + i * 64 + j0 + e];
  }
  __syncthreads();
  for (int t = 0; t < 64; ++t) {
    float v = Vc[t][i];
    float y = 0.f;
    #pragma unroll
    for (int e = 0; e < 16; ++e) {
      s[e] = r[e] * s[e] + g[e] * (v * Kc[t][j0 + e]);
      y += (w[e] + s[e]) * Qc[t][j0 + e];
    }
    y += __shfl_xor(y, 1);
    y += __shfl_xor(y, 2);
    if ((tid & 3) == 0)
      ystp[((size_t)h * L_SEQ + c * 64 + t) * 64 + i] = y;
  }
}

// ---------------- gate tail (bf16 g) ----------------------------------------
__global__ __launch_bounds__(256) void gate2_kernel(const short* __restrict__ g_bf,
    const float* __restrict__ w2, const float* __restrict__ b2,
    float* __restrict__ alpha)
{
  int gid = blockIdx.x * 256 + threadIdx.x;
  int l = gid >> 4, h = gid & 15;
  float acc = b2[h];
  const short* grow = g_bf + (size_t)l * 512;
  for (int c2 = 0; c2 < 512; c2 += 2) {
    u32 pk = *(const u32*)(grow + c2);
    float g0 = __uint_as_float(pk << 16);
    float g1 = __uint_as_float(pk & 0xffff0000u);
    acc += g0 * w2[c2 * 16 + h] + g1 * w2[(c2 + 1) * 16 + h];
  }
  alpha[gid] = 1.f / (1.f + expf(-acc));
}

// ---------------- combine + transpose -> bf16 (L, D) ------------------------
__global__ __launch_bounds__(256) void combine_kernel(const float* __restrict__ ysm,
    const float* __restrict__ ystp, const float* __restrict__ alpha,
    short* __restrict__ ycb)
{
  int gid = blockIdx.x * 256 + threadIdx.x;
  int l = gid >> 10, cidx = gid & 1023;
  int h = cidx >> 6, e = cidx & 63;
  float a = alpha[l * 16 + h];
  size_t src = ((size_t)h * L_SEQ + l) * 64 + e;
  ycb[gid] = f2bf(a * ysm[src] + (1.f - a) * ystp[src]);
}

extern "C" void kernel_launch(void* const* d_in, const int* in_sizes, int n_in,
                              void* d_out, int out_size, void* d_ws, size_t ws_size,
                              hipStream_t stream) {
  (void)in_sizes; (void)n_in; (void)out_size; (void)ws_size;
  const float* x      = (const float*)d_in[0];
  const float* Wqkv_w = (const float*)d_in[1];
  const float* Wqkv_b = (const float*)d_in[2];
  const float* out_w  = (const float*)d_in[3];
  const float* out_b  = (const float*)d_in[4];
  const float* W_st   = (const float*)d_in[5];
  const float* Lam    = (const float*)d_in[6];
  const float* Gam    = (const float*)d_in[7];
  const float* gw1    = (const float*)d_in[8];
  const float* gb1    = (const float*)d_in[9];
  const float* gw2    = (const float*)d_in[10];
  const float* gb2    = (const float*)d_in[11];

  float* ws     = (float*)d_ws;
  float* qkv    = ws;                        // 2048x3072 fp32
  float* ysm    = ws + 6291456;
  float* ystp   = ws + 8388608;
  float* states = ws + 10485760;
  float* ovl    = ws + 12582912;             // overlay span: 3670016 floats
  float* alpha  = ws + 16252928;             // total 65.1 MB
  // phase 1 overlay
  short* xb     = (short*)ovl;                      // 2048x1024 bf16
  short* wt_buf = (short*)(ovl + 1048576);          // 3584x1024 bf16
  short* g_bf   = (short*)(ovl + 2883584);          // 2048x512 bf16
  // phase 2 overlay
  short* Qb     = (short*)ovl;
  short* Kb     = (short*)(ovl + 1048576);
  short* Vtb    = (short*)(ovl + 2097152);
  // phase 3 overlay
  short* wtO    = (short*)ovl;                      // 1024x1024 bf16
  short* ycb    = (short*)states;                   // states dead after stp_out

  // phase 1: fused qkv+gate projection
  conv_x<<<dim3(2048), 256, 0, stream>>>(x, xb);
  transpose_conv<<<dim3(96, 32), 256, 0, stream>>>(Wqkv_w, wt_buf, 1024, 3072);
  transpose_conv<<<dim3(16, 32), 256, 0, stream>>>(gw1, wt_buf + 3072 * 1024, 1024, 512);
  gemm_mfma<128, 128, 2><<<dim3(28, 16), 256, 0, stream>>>(
      xb, wt_buf, Wqkv_b, gb1, qkv, g_bf, 2048, 3584, 1024);
  gate2_kernel<<<dim3(128), 256, 0, stream>>>(g_bf, gw2, gb2, alpha);
  // STP branch (fp32 qkv)
  stp_local<<<dim3(32, 16), 256, 0, stream>>>(qkv, Lam, Gam, states);
  stp_scan<<<dim3(256), 256, 0, stream>>>(Lam, states);
  stp_out<<<dim3(32, 16), 256, 0, stream>>>(qkv, Lam, Gam, W_st, states, ystp);
  // phase 2: attention
  conv_qkv<<<dim3(32, 16), 256, 0, stream>>>(qkv, Qb, Kb, Vtb);
  attn_mfma<<<dim3(512), 256, 0, stream>>>(Qb, Kb, Vtb, ysm);
  combine_kernel<<<dim3(8192), 256, 0, stream>>>(ysm, ystp, alpha, ycb);
  // phase 3: out projection
  transpose_conv<<<dim3(32, 32), 256, 0, stream>>>(out_w, wtO, 1024, 1024);
  gemm_mfma<64, 128, 0><<<dim3(8, 32), 256, 0, stream>>>(
      ycb, wtO, out_b, nullptr, (float*)d_out, nullptr, 2048, 1024, 1024);
}